// Round 4
// baseline (213.826 us; speedup 1.0000x reference)
//
#include <hip/hip_runtime.h>

// Problem constants (fixed by the reference)
#define BB 1024
#define LL 256
#define DD 64
#define TDIM 100

#define BIG 3.0e38f          // +INF stand-in (avoids fast-math inf pitfalls)
#define TBL_OFF 256          // float offset of tables in d_ws

// ---------------------------------------------------------------------------
// Piecewise-linear factorization of the MLP:
//   f(c)[d] = sum_e relu(c*w1[e]+b1[e]) * w2[e][d]
// For c >= 0 the relu active set changes only at positive thresholds
// tau_e = -b1[e]/w1[e]. Within segment k:  f(c)[d] = c*A_k[d] + B_k[d].
// Prep kernel (1 block, 64 threads) sorts thresholds, builds A/B' prefix
// tables (B' = B + b2, so two-side sum yields exactly +2*b2).
// d_ws layout (floats): [0..63] bp sorted asc, padded BIG;
//                       [TBL_OFF + k*128 + ch*8 + {0..3}] = A_k[4ch..4ch+3]
//                       [TBL_OFF + k*128 + ch*8 + {4..7}] = B'_k[4ch..4ch+3]
// ---------------------------------------------------------------------------
__global__ void tni_prep(const float* __restrict__ w1, const float* __restrict__ b1,
                         const float* __restrict__ w2, const float* __restrict__ b2,
                         float* __restrict__ ws)
{
    __shared__ float tauS[DD];
    __shared__ int   vS[DD];
    __shared__ float bpS[DD];
    __shared__ int   beS[DD];

    const int t = threadIdx.x;           // 0..63
    float we = w1[t], be = b1[t];
    float tau = -be / we;
    // breakpoints only matter for c in [0, 256); filter with margin
    int valid = (we != 0.0f) && (tau > 0.0f) && (tau < 1.0e3f);
    tauS[t] = tau; vS[t] = valid;
    bpS[t] = BIG;  beS[t] = 0;
    __syncthreads();

    int rank = 0;
    for (int j = 0; j < DD; ++j) {
        if (vS[j] && (tauS[j] < tau || (tauS[j] == tau && j < t))) rank++;
    }
    __syncthreads();
    if (valid) { bpS[rank] = tau; beS[rank] = t; }
    __syncthreads();

    ws[t] = bpS[t];                       // publish sorted breakpoints

    // Tables: thread owns output dim d = t. Segment 0 active set probed at
    // c0 strictly inside (0, bp0); affine predicate needs no case analysis.
    float c0 = fminf(bpS[0] * 0.5f, 1.0f);
    float A  = 0.0f;
    float Bv = b2[t];                     // bake b2 into B'
    for (int e = 0; e < DD; ++e) {
        float w1e = w1[e], b1e = b1[e];   // uniform -> scalar loads
        float w2r = w2[e*DD + t];         // coalesced across threads
        if (fmaf(c0, w1e, b1e) > 0.0f) {
            A  = fmaf(w1e, w2r, A);
            Bv = fmaf(b1e, w2r, Bv);
        }
    }
    float* tbl = ws + TBL_OFF;
    tbl[(t>>2)*8     + (t&3)] = A;
    tbl[(t>>2)*8 + 4 + (t&3)] = Bv;
    for (int i = 0; i < DD; ++i) {
        if (bpS[i] > 1.0e38f) break;      // i >= m (uniform branch)
        int   e   = beS[i];
        float w1e = w1[e], b1e = b1[e];
        float w2r = w2[e*DD + t];
        float s   = (w1e > 0.0f) ? 1.0f : -1.0f;  // crossing up: +on / -off
        A  = fmaf(s*w1e, w2r, A);
        Bv = fmaf(s*b1e, w2r, Bv);
        tbl[(i+1)*128 + (t>>2)*8     + (t&3)] = A;
        tbl[(i+1)*128 + (t>>2)*8 + 4 + (t&3)] = Bv;
    }
}

// ---------------------------------------------------------------------------
// Main kernel: one block = (batch row, side). Thread t owns position t:
//   O(L) uniform-load count scan -> cos/sigmoid weight -> segment search
// then phase 2 re-tiles so stores are lane-contiguous float4 (1KB/wave-inst).
// LDS ~4.5KB, no MFMA, launch_bounds(256,6) for 6 waves/SIMD latency hiding.
// ---------------------------------------------------------------------------
__global__ __launch_bounds__(256, 6) void tni_main(
    const int* __restrict__ src_ids, const int* __restrict__ dst_ids,
    const float* __restrict__ src_tm, const float* __restrict__ dst_tm,
    const float* __restrict__ node_tm,
    const float* __restrict__ w_time, const float* __restrict__ b_time,
    const float* __restrict__ w_ts, const float* __restrict__ b_ts,
    const float* __restrict__ ws, float* __restrict__ out)
{
    __shared__ float  bpS[DD];
    __shared__ float4 cv[LL];             // (c1w, c2w, bits(k1), bits(k2))

    const int t    = threadIdx.x;
    const int b    = blockIdx.x >> 1;
    const int side = blockIdx.x & 1;

    if (t < DD) bpS[t] = ws[t];

    const int*   my_ids = side ? dst_ids : src_ids;
    const float* my_tms = side ? dst_tm  : src_tm;
    const int   my_id = my_ids[b*LL + t];
    const float my_tm = my_tms[b*LL + t];

    // counts: scan both id rows (wave-uniform addresses -> scalar/L1-hot)
    const int4* sr4 = (const int4*)(src_ids + b*LL);
    const int4* dr4 = (const int4*)(dst_ids + b*LL);
    int c1 = 0, c2 = 0;
    #pragma unroll 2
    for (int j = 0; j < LL/4; ++j) {
        int4 a  = sr4[j];
        int4 dd = dr4[j];
        c1 += (a.x==my_id) + (a.y==my_id) + (a.z==my_id) + (a.w==my_id);
        c2 += (dd.x==my_id) + (dd.y==my_id) + (dd.z==my_id) + (dd.w==my_id);
    }
    if (my_id == 0) { c1 = 0; c2 = 0; }   // padding id -> zero count

    // time weight: sigmoid(cos(td*w+b) @ w_ts + b_ts); v_cos takes revolutions
    const float inv2pi = 0.15915494309189535f;
    float td = node_tm[b] - my_tm;
    float z  = b_ts[0];
    #pragma unroll 4
    for (int k = 0; k < TDIM; ++k) {
        float u = fmaf(td, w_time[k], b_time[k]);
        float r = __builtin_amdgcn_fractf(u * inv2pi);
        z = fmaf(__builtin_amdgcn_cosf(r), w_ts[k], z);
    }
    float ee  = __builtin_amdgcn_exp2f(-1.44269504f * z);
    float wgt = __builtin_amdgcn_rcpf(1.0f + ee);
    float c1w = (float)c1 * wgt;
    float c2w = (float)c2 * wgt;

    __syncthreads();                      // bpS ready

    // branchless binary search: k = #{bp_i < c} over 64 sorted (BIG-padded)
    int k1 = 0, k2 = 0;
    #pragma unroll
    for (int s = 32; s >= 1; s >>= 1) {
        k1 += (bpS[k1 + s - 1] < c1w) ? s : 0;
        k2 += (bpS[k2 + s - 1] < c2w) ? s : 0;
    }
    k1 += (bpS[k1] < c1w) ? 1 : 0;        // 64th-entry fixup
    k2 += (bpS[k2] < c2w) ? 1 : 0;

    cv[t] = make_float4(c1w, c2w, __int_as_float(k1), __int_as_float(k2));
    __syncthreads();

    // phase 2: wave w covers positions w*64..w*64+63; per step, 4 rows x 16
    // d-chunks -> lane-contiguous float4 stores (1KB per wave-instruction)
    const int w  = t >> 6;
    const int l  = t & 63;
    const int pq = l >> 4;                // row-within-4
    const int ch = l & 15;                // d-chunk (4 floats)
    const float* tbl = ws + TBL_OFF;
    const int obase = side * (BB*LL*DD) + b * (LL*DD);

    #pragma unroll 4
    for (int s = 0; s < 16; ++s) {
        int p = w*64 + s*4 + pq;
        float4 c = cv[p];
        int ka = __float_as_int(c.z), kb = __float_as_int(c.w);
        const float4* r1 = (const float4*)(tbl + ka*128 + ch*8);
        const float4* r2 = (const float4*)(tbl + kb*128 + ch*8);
        float4 A1 = r1[0], B1 = r1[1];
        float4 A2 = r2[0], B2 = r2[1];
        float4 o;
        o.x = fmaf(c.x, A1.x, B1.x) + fmaf(c.y, A2.x, B2.x);
        o.y = fmaf(c.x, A1.y, B1.y) + fmaf(c.y, A2.y, B2.y);
        o.z = fmaf(c.x, A1.z, B1.z) + fmaf(c.y, A2.z, B2.z);
        o.w = fmaf(c.x, A1.w, B1.w) + fmaf(c.y, A2.w, B2.w);
        *(float4*)(out + obase + p*DD + ch*4) = o;
    }
}

extern "C" void kernel_launch(void* const* d_in, const int* in_sizes, int n_in,
                              void* d_out, int out_size, void* d_ws, size_t ws_size,
                              hipStream_t stream) {
    const int* src_ids = (const int*)d_in[0];
    const int* dst_ids = (const int*)d_in[1];
    const float* src_tm  = (const float*)d_in[2];
    const float* dst_tm  = (const float*)d_in[3];
    const float* node_tm = (const float*)d_in[4];
    // d_in[5] = num_nodes (unused: counts via direct id comparison)
    const float* w_time = (const float*)d_in[6];
    const float* b_time = (const float*)d_in[7];
    const float* w_ts   = (const float*)d_in[8];
    const float* b_ts   = (const float*)d_in[9];
    const float* w1     = (const float*)d_in[10];
    const float* b1     = (const float*)d_in[11];
    const float* w2     = (const float*)d_in[12];
    const float* b2     = (const float*)d_in[13];
    float* out = (float*)d_out;
    float* ws  = (float*)d_ws;

    tni_prep<<<dim3(1), dim3(64), 0, stream>>>(w1, b1, w2, b2, ws);
    tni_main<<<dim3(BB*2), dim3(256), 0, stream>>>(
        src_ids, dst_ids, src_tm, dst_tm, node_tm,
        w_time, b_time, w_ts, b_ts, ws, out);
}

// Round 5
// 203.763 us; speedup vs baseline: 1.0494x; 1.0494x over previous
//
#include <hip/hip_runtime.h>

// Problem constants (fixed by the reference)
#define BB 1024
#define LL 256
#define DD 64
#define TDIM 100
#define NNODES 20000
#define HWORDS ((NNODES + 1) / 2)   // 10000 packed-u16 words
#define BIG 3.0e38f
#define TBL_OFF 256                 // float offset of tables in d_ws

// ---------------------------------------------------------------------------
// Piecewise-linear factorization of the MLP:
//   f(c)[d] = sum_e relu(c*w1[e]+b1[e]) * w2[e][d]   (c >= 0)
// Active set changes only at positive thresholds tau_e = -b1[e]/w1[e].
// Segment k (between sorted breakpoints): f(c)[d] = c*A_k[d] + B'_k[d],
// B' bakes in b2 so summing two sides gives exactly +2*b2.
//
// Prep: 65 blocks (one per segment) x 64 threads (one per output dim d).
// Each block rank-sorts the thresholds (cheap, duplicated) and evaluates the
// active set DIRECTLY at the segment midpoint -- fully parallel, no serial
// cross-iteration dependency (R4's 1-block serial prep was ~+25us).
// d_ws floats: [0..63] sorted breakpoints (BIG-padded);
//   [TBL_OFF + k*128 + ch*8 + {0..3}] = A_k[4ch..4ch+3]
//   [TBL_OFF + k*128 + ch*8 + {4..7}] = B'_k[4ch..4ch+3]
// ---------------------------------------------------------------------------
__global__ void tni_prep(const float* __restrict__ w1, const float* __restrict__ b1,
                         const float* __restrict__ w2, const float* __restrict__ b2,
                         float* __restrict__ ws)
{
    __shared__ float tauS[DD];
    __shared__ int   vS[DD];
    __shared__ float bpS[DD];
    __shared__ float w1S[DD], b1S[DD];

    const int t = threadIdx.x;            // output dim d
    const int k = blockIdx.x;             // segment 0..64

    float we = w1[t], be = b1[t];
    w1S[t] = we; b1S[t] = be;
    float tau = -be / we;
    // c = count*sigmoid <= 256, so thresholds >= 1e3 never flip in range
    int valid = (we != 0.0f) && (tau > 0.0f) && (tau < 1.0e3f);
    tauS[t] = tau; vS[t] = valid; bpS[t] = BIG;
    __syncthreads();

    int rank = 0;
    for (int j = 0; j < DD; ++j)
        if (vS[j] && (tauS[j] < tau || (tauS[j] == tau && j < t))) rank++;
    __syncthreads();
    if (valid) bpS[rank] = tau;
    __syncthreads();

    if (k == 0) ws[t] = bpS[t];           // publish sorted breakpoints once

    // probe point strictly inside segment k; cap keeps it finite/in-range
    float lo = (k == 0) ? 0.0f : bpS[k-1];
    float hi = (k < DD) ? bpS[k] : BIG;
    float ct = fminf(0.5f * (lo + hi), 1.0e3f);

    float A = 0.0f, Bv = b2[t];           // bake b2 into B'
    for (int e = 0; e < DD; ++e) {
        float w1e = w1S[e], b1e = b1S[e];     // LDS broadcast
        float w2r = w2[e*DD + t];             // coalesced
        if (fmaf(ct, w1e, b1e) > 0.0f) {
            A  = fmaf(w1e, w2r, A);
            Bv = fmaf(b1e, w2r, Bv);
        }
    }
    float* tbl = ws + TBL_OFF;
    tbl[k*128 + (t>>2)*8     + (t&3)] = A;
    tbl[k*128 + (t>>2)*8 + 4 + (t&3)] = Bv;
}

// ---------------------------------------------------------------------------
// Main: one block per batch row b, BOTH sides (512 positions, 256 threads).
// Counts via packed-u16 LDS histogram with touched-word clears: O(L) not
// O(L^2). Predicated add == reference's id!=0 mask (gather at id 0 reads a
// cleared half-word -> 0). Two epochs reuse one 40KB histogram.
// LDS ~49.6KB -> 3 blocks/CU.
// ---------------------------------------------------------------------------
__global__ __launch_bounds__(256, 3) void tni_main(
    const int* __restrict__ src_ids, const int* __restrict__ dst_ids,
    const float* __restrict__ src_tm, const float* __restrict__ dst_tm,
    const float* __restrict__ node_tm,
    const float* __restrict__ w_time, const float* __restrict__ b_time,
    const float* __restrict__ w_ts, const float* __restrict__ b_ts,
    const float* __restrict__ ws, float* __restrict__ out)
{
    __shared__ unsigned int hist[HWORDS];  // 40000 B
    __shared__ float4 cv[2*LL];            // 8192 B: (cA, cB, bits kA, bits kB)
    __shared__ float wco[TDIM], bco[TDIM], sco[TDIM];
    __shared__ float bpS[DD];

    const int t = threadIdx.x;
    const int b = blockIdx.x;

    const int   sid = src_ids[b*LL + t];
    const int   did = dst_ids[b*LL + t];
    const float stm = src_tm[b*LL + t];
    const float dtm = dst_tm[b*LL + t];

    if (t < TDIM) {
        const float inv2pi = 0.15915494309189535f;  // v_cos takes revolutions
        wco[t] = w_time[t] * inv2pi;
        bco[t] = b_time[t] * inv2pi;
        sco[t] = w_ts[t];
    }
    if (t < DD) bpS[t] = ws[t];

    const int sw = sid >> 1, ssh = (sid & 1) * 16;
    const int dw = did >> 1, dsh = (did & 1) * 16;

    // epoch 1: src-row histogram
    hist[sw] = 0; hist[dw] = 0;            // clear only touched words
    __syncthreads();
    if (sid) atomicAdd(&hist[sw], 1u << ssh);
    __syncthreads();
    const unsigned css = (hist[sw] >> ssh) & 0xffffu;  // src id in src row
    const unsigned cds = (hist[dw] >> dsh) & 0xffffu;  // dst id in src row
    __syncthreads();
    // epoch 2: dst-row histogram
    hist[sw] = 0; hist[dw] = 0;
    __syncthreads();
    if (did) atomicAdd(&hist[dw], 1u << dsh);
    __syncthreads();
    const unsigned csd = (hist[sw] >> ssh) & 0xffffu;  // src id in dst row
    const unsigned cdd = (hist[dw] >> dsh) & 0xffffu;  // dst id in dst row

    // time weights: two interleaved cos chains (ILP)
    const float ntm = node_tm[b];
    float tds = ntm - stm, tdd = ntm - dtm;
    float zs = b_ts[0], zd = zs;
    #pragma unroll 4
    for (int k = 0; k < TDIM; ++k) {
        float w = wco[k], bb = bco[k], s = sco[k];
        float rs = __builtin_amdgcn_fractf(fmaf(tds, w, bb));
        float rd = __builtin_amdgcn_fractf(fmaf(tdd, w, bb));
        zs = fmaf(__builtin_amdgcn_cosf(rs), s, zs);
        zd = fmaf(__builtin_amdgcn_cosf(rd), s, zd);
    }
    float wgs = __builtin_amdgcn_rcpf(1.0f + __builtin_amdgcn_exp2f(-1.44269504f * zs));
    float wgd = __builtin_amdgcn_rcpf(1.0f + __builtin_amdgcn_exp2f(-1.44269504f * zd));

    float cA0 = (float)css * wgs, cB0 = (float)csd * wgs;  // src side
    float cA1 = (float)cds * wgd, cB1 = (float)cdd * wgd;  // dst side

    // 4 branchless binary searches: k = #{bp < c} over 64 sorted (BIG-padded)
    int kA0 = 0, kB0 = 0, kA1 = 0, kB1 = 0;
    #pragma unroll
    for (int s = 32; s >= 1; s >>= 1) {
        kA0 += (bpS[kA0 + s - 1] < cA0) ? s : 0;
        kB0 += (bpS[kB0 + s - 1] < cB0) ? s : 0;
        kA1 += (bpS[kA1 + s - 1] < cA1) ? s : 0;
        kB1 += (bpS[kB1 + s - 1] < cB1) ? s : 0;
    }
    kA0 += (bpS[kA0] < cA0) ? 1 : 0;
    kB0 += (bpS[kB0] < cB0) ? 1 : 0;
    kA1 += (bpS[kA1] < cA1) ? 1 : 0;
    kB1 += (bpS[kB1] < cB1) ? 1 : 0;

    cv[t]      = make_float4(cA0, cB0, __int_as_float(kA0), __int_as_float(kB0));
    cv[LL + t] = make_float4(cA1, cB1, __int_as_float(kA1), __int_as_float(kB1));
    __syncthreads();

    // phase 2: wave w owns q in [w*128, w*128+128); per step 4 rows x 16
    // d-chunks -> lane-contiguous 1KB float4 stores. q<256: src, else dst.
    const int w  = t >> 6;
    const int l  = t & 63;
    const int pq = l >> 4;
    const int ch = l & 15;
    const float* tbl = ws + TBL_OFF;
    const size_t halfo = (size_t)BB * LL * DD;

    #pragma unroll 4
    for (int s = 0; s < 32; ++s) {
        int q = w*128 + s*4 + pq;
        float4 c = cv[q];
        int ka = __float_as_int(c.z), kb = __float_as_int(c.w);
        const float4* r1 = (const float4*)(tbl + ka*128 + ch*8);
        const float4* r2 = (const float4*)(tbl + kb*128 + ch*8);
        float4 A1 = r1[0], B1 = r1[1];
        float4 A2 = r2[0], B2 = r2[1];
        float4 o;
        o.x = fmaf(c.x, A1.x, B1.x) + fmaf(c.y, A2.x, B2.x);
        o.y = fmaf(c.x, A1.y, B1.y) + fmaf(c.y, A2.y, B2.y);
        o.z = fmaf(c.x, A1.z, B1.z) + fmaf(c.y, A2.z, B2.z);
        o.w = fmaf(c.x, A1.w, B1.w) + fmaf(c.y, A2.w, B2.w);
        int side = q >> 8, p = q & (LL-1);
        *(float4*)(out + (size_t)side*halfo + (size_t)b*(LL*DD) + p*DD + ch*4) = o;
    }
}

extern "C" void kernel_launch(void* const* d_in, const int* in_sizes, int n_in,
                              void* d_out, int out_size, void* d_ws, size_t ws_size,
                              hipStream_t stream) {
    const int* src_ids = (const int*)d_in[0];
    const int* dst_ids = (const int*)d_in[1];
    const float* src_tm  = (const float*)d_in[2];
    const float* dst_tm  = (const float*)d_in[3];
    const float* node_tm = (const float*)d_in[4];
    // d_in[5] = num_nodes (fixed 20000; counts via LDS histogram)
    const float* w_time = (const float*)d_in[6];
    const float* b_time = (const float*)d_in[7];
    const float* w_ts   = (const float*)d_in[8];
    const float* b_ts   = (const float*)d_in[9];
    const float* w1     = (const float*)d_in[10];
    const float* b1     = (const float*)d_in[11];
    const float* w2     = (const float*)d_in[12];
    const float* b2     = (const float*)d_in[13];
    float* out = (float*)d_out;
    float* ws  = (float*)d_ws;

    tni_prep<<<dim3(DD+1), dim3(DD), 0, stream>>>(w1, b1, w2, b2, ws);
    tni_main<<<dim3(BB), dim3(256), 0, stream>>>(
        src_ids, dst_ids, src_tm, dst_tm, node_tm,
        w_time, b_time, w_ts, b_ts, ws, out);
}

// Round 6
// 168.479 us; speedup vs baseline: 1.2692x; 1.2094x over previous
//
#include <hip/hip_runtime.h>

// Problem constants (fixed by the reference)
#define BB 1024
#define LL 256
#define DD 64
#define TDIM 100
#define NNODES 20000
#define HWORDS ((NNODES + 1) / 2)   // 10000 packed-u16 words

typedef _Float16 half8_t __attribute__((ext_vector_type(8)));
typedef float f32x4 __attribute__((ext_vector_type(4)));

// One block = one (batch row, side) pair. side 0 -> src features, 1 -> dst.
// Threads: 256 (4 waves). Thread t owns position t of the row.
//
// R2 structure (measured best: 176us) with ONE change: the O(L^2) LDS id
// scan (128 ds_read_b128/thread ~= 20us of LDS-pipe time across the grid)
// is replaced by an O(L) packed-u16 LDS histogram. The 40KB histogram
// ALIASES the W2v/Gv staging region (union: hist phase fully precedes
// staging). Everything else -- MFMA tiling, epilogue, launch bounds,
// LDS-resident coeffs -- is unchanged from R2.
__global__ __launch_bounds__(256, 2) void tni_kernel(
    const int* __restrict__ src_ids, const int* __restrict__ dst_ids,
    const float* __restrict__ src_tm, const float* __restrict__ dst_tm,
    const float* __restrict__ node_tm,
    const float* __restrict__ w_time, const float* __restrict__ b_time,
    const float* __restrict__ w_ts, const float* __restrict__ b_ts,
    const float* __restrict__ w1, const float* __restrict__ b1,
    const float* __restrict__ w2, const float* __restrict__ b2,
    float* __restrict__ out)
{
    // 40,960B union: [hist: 10000 u32] | [W2v: 8KB (2048 u32) + Gv: 32KB]
    __shared__ unsigned int uS[10240];
    __shared__ float wrv[TDIM], brv[TDIM], wtsv[TDIM]; // coeffs (revolutions)
    __shared__ float w1v[DD], b1v[DD];

    unsigned int* hist = uS;
    half8_t* W2v = (half8_t*)uS;             // [DD*8], valid after hist phase
    half8_t* Gv  = (half8_t*)(uS + 2048);    // [LL*8]

    const int t    = threadIdx.x;
    const int b    = blockIdx.x >> 1;
    const int side = blockIdx.x & 1;

    // ---- per-thread inputs (issued early, coalesced) ----
    const int   sid   = src_ids[b*LL + t];
    const int   did   = dst_ids[b*LL + t];
    const float my_tm = side ? dst_tm[b*LL + t] : src_tm[b*LL + t];

    // prefetch w2 into registers; LDS write deferred until hist region frees
    float w2r[16];
    #pragma unroll
    for (int i = 0; i < 16; ++i) w2r[i] = w2[t + 256*i];

    if (t < TDIM) {
        const float inv2pi = 0.15915494309189535f;   // v_cos_f32 takes revolutions
        wrv[t]  = w_time[t] * inv2pi;
        brv[t]  = b_time[t] * inv2pi;
        wtsv[t] = w_ts[t];
    }
    if (t < DD) {
        w1v[t] = w1[t];
        b1v[t] = b1[t];
    }

    // ---- counts via packed-u16 histogram, clears limited to touched words ----
    const int sw = sid >> 1, ssh = (sid & 1) * 16;
    const int dw = did >> 1, dsh = (did & 1) * 16;
    const int myw  = side ? dw  : sw;
    const int mysh = side ? dsh : ssh;
    const int my_id = side ? did : sid;

    // epoch A: histogram of the src row -> count of my_id in src row (c1)
    hist[sw] = 0; hist[dw] = 0;
    __syncthreads();
    if (sid) atomicAdd(&hist[sw], 1u << ssh);
    __syncthreads();
    unsigned c1 = (hist[myw] >> mysh) & 0xffffu;
    __syncthreads();
    // epoch B: histogram of the dst row -> count of my_id in dst row (c2)
    hist[sw] = 0; hist[dw] = 0;
    __syncthreads();
    if (did) atomicAdd(&hist[dw], 1u << dsh);
    __syncthreads();
    unsigned c2 = (hist[myw] >> mysh) & 0xffffu;
    if (my_id == 0) { c1 = 0; c2 = 0; }   // padding id -> zero count (mask)
    __syncthreads();                       // hist reads done; region reusable

    // ---- time weight: sigmoid(cos(td*w+b) @ w_ts + b_ts) ----
    float td = node_tm[b] - my_tm;
    float z  = b_ts[0];
    #pragma unroll 4
    for (int k = 0; k < TDIM; ++k) {
        float r = fmaf(td, wrv[k], brv[k]);
        r -= floorf(r);                               // reduce to [0,1) revolutions
        z = fmaf(__builtin_amdgcn_cosf(r), wtsv[k], z);
    }
    float ee  = __builtin_amdgcn_exp2f(-1.44269504f * z);  // exp(-z)
    float wgt = __builtin_amdgcn_rcpf(1.0f + ee);          // sigmoid(z)
    float c1w = (float)c1 * wgt;
    float c2w = (float)c2 * wgt;

    // ---- stage w2 (from regs) -> W2v = w2^T rows [d][e] fp16, swizzled ----
    {
        _Float16* w2s = (_Float16*)W2v;
        #pragma unroll
        for (int i = 0; i < 16; ++i) {
            int idx = t + 256*i;            // 0..4095
            int e = idx >> 6, d = idx & 63;
            int chunk = (e >> 3) ^ (d & 7); // XOR swizzle on 16B chunks within a row
            w2s[d*64 + (chunk << 3) + (e & 7)] = (_Float16)w2r[i];
        }
    }

    // ---- g[e] = relu(c1w*w1+b1) + relu(c2w*w1+b1), fp16 into A-fragment LDS ----
    #pragma unroll
    for (int c = 0; c < 8; ++c) {
        half8_t h;
        #pragma unroll
        for (int j = 0; j < 8; ++j) {
            float w1e = w1v[c*8 + j], b1e = b1v[c*8 + j];
            float g = fmaxf(fmaf(c1w, w1e, b1e), 0.f)
                    + fmaxf(fmaf(c2w, w1e, b1e), 0.f);
            h[j] = (_Float16)g;
        }
        Gv[t*8 + (c ^ (t & 7))] = h;      // row t, swizzled chunk
    }
    __syncthreads();

    // ---- MFMA: [256 x 64] x [64 x 64], wave w owns rows 64w..64w+63 ----
    const int w    = t >> 6;
    const int l    = t & 63;
    const int quad = l >> 4;
    const int lr   = l & 15;

    f32x4 acc[4][4];
    #pragma unroll
    for (int mt = 0; mt < 4; ++mt)
        #pragma unroll
        for (int nt = 0; nt < 4; ++nt) {
            f32x4 zz = {0.f, 0.f, 0.f, 0.f};
            acc[mt][nt] = zz;
        }

    #pragma unroll
    for (int s = 0; s < 2; ++s) {         // K steps of 32
        const int c = s*4 + quad;         // logical 16B chunk (8 k's) this lane reads
        half8_t bfr[4], afr[4];
        #pragma unroll
        for (int nt = 0; nt < 4; ++nt) {  // B: lane holds B[k=quad*8+j][n=lane&15] = w2T row n
            int n = nt*16 + lr;
            bfr[nt] = W2v[n*8 + (c ^ (n & 7))];
        }
        #pragma unroll
        for (int mt = 0; mt < 4; ++mt) {  // A: lane holds A[m=lane&15][k=quad*8+j]
            int row = w*64 + mt*16 + lr;
            afr[mt] = Gv[row*8 + (c ^ (row & 7))];
        }
        #pragma unroll
        for (int mt = 0; mt < 4; ++mt)
            #pragma unroll
            for (int nt = 0; nt < 4; ++nt)
                acc[mt][nt] = __builtin_amdgcn_mfma_f32_16x16x32_f16(
                    afr[mt], bfr[nt], acc[mt][nt], 0, 0, 0);
    }

    // ---- epilogue: +2*b2, store fp32. C layout: col=lane&15, row=quad*4+reg ----
    float b2v[4];
    #pragma unroll
    for (int nt = 0; nt < 4; ++nt)
        b2v[nt] = 2.f * b2[nt*16 + lr];

    const int obase = side * (BB*LL*DD) + b * (LL*DD);
    #pragma unroll
    for (int mt = 0; mt < 4; ++mt) {
        #pragma unroll
        for (int r = 0; r < 4; ++r) {
            int pos = w*64 + mt*16 + quad*4 + r;
            #pragma unroll
            for (int nt = 0; nt < 4; ++nt) {
                out[obase + pos*DD + nt*16 + lr] = acc[mt][nt][r] + b2v[nt];
            }
        }
    }
}

extern "C" void kernel_launch(void* const* d_in, const int* in_sizes, int n_in,
                              void* d_out, int out_size, void* d_ws, size_t ws_size,
                              hipStream_t stream) {
    const int* src_ids = (const int*)d_in[0];
    const int* dst_ids = (const int*)d_in[1];
    const float* src_tm  = (const float*)d_in[2];
    const float* dst_tm  = (const float*)d_in[3];
    const float* node_tm = (const float*)d_in[4];
    // d_in[5] = num_nodes (fixed 20000; counts via LDS histogram)
    const float* w_time = (const float*)d_in[6];
    const float* b_time = (const float*)d_in[7];
    const float* w_ts   = (const float*)d_in[8];
    const float* b_ts   = (const float*)d_in[9];
    const float* w1     = (const float*)d_in[10];
    const float* b1     = (const float*)d_in[11];
    const float* w2     = (const float*)d_in[12];
    const float* b2     = (const float*)d_in[13];
    float* out = (float*)d_out;

    tni_kernel<<<dim3(BB*2), dim3(256), 0, stream>>>(
        src_ids, dst_ids, src_tm, dst_tm, node_tm,
        w_time, b_time, w_ts, b_ts, w1, b1, w2, b2, out);
}